// Round 6
// baseline (508.358 us; speedup 1.0000x reference)
//
#include <hip/hip_runtime.h>
#include <hip/hip_fp16.h>

#define N_NODES 50000
#define N_EDGES 800000
#define D 64

// ---------------------------------------------------------------------------
// Workspace layout:
//   agg     : __half[N_NODES*D]  6.4 MB   (memset 0)
//   out_deg : int[N_NODES]                (memset 0)
//   in_deg  : int[N_NODES]                (memset 0)
//   y       : __half[N_NODES*D]  6.4 MB   (fully overwritten, no memset)
// ---------------------------------------------------------------------------
#define AGG_OFF     0
#define OUTDEG_OFF  (N_NODES * D * 2)
#define INDEG_OFF   (OUTDEG_OFF + N_NODES * 4)
#define Y_OFF       (INDEG_OFF + N_NODES * 4)
#define ZERO_BYTES  Y_OFF

// 4 edges per thread via int4: both degree histograms.
__global__ void degree_kernel(const int* __restrict__ src,
                              const int* __restrict__ dst,
                              int* __restrict__ out_deg,
                              int* __restrict__ in_deg) {
    int e4 = blockIdx.x * blockDim.x + threadIdx.x;
    if (e4 < N_EDGES / 4) {
        int4 s = ((const int4*)src)[e4];
        int4 d = ((const int4*)dst)[e4];
        atomicAdd(&out_deg[s.x], 1);
        atomicAdd(&out_deg[s.y], 1);
        atomicAdd(&out_deg[s.z], 1);
        atomicAdd(&out_deg[s.w], 1);
        atomicAdd(&in_deg[d.x], 1);
        atomicAdd(&in_deg[d.y], 1);
        atomicAdd(&in_deg[d.z], 1);
        atomicAdd(&in_deg[d.w], 1);
    }
}

// y[n][j] = fp16( x[n][j] * rsqrt(max(out_deg[n],1)) ), one half2 per thread.
__global__ void yscale_kernel(const float* __restrict__ x,
                              const int* __restrict__ out_deg,
                              __half2* __restrict__ y2) {
    int t = blockIdx.x * blockDim.x + threadIdx.x;
    if (t < N_NODES * (D / 2)) {
        int n = t >> 5;                 // D/2 = 32 half2 per node
        float2 v = ((const float2*)x)[t];
        float s = rsqrtf(fmaxf((float)out_deg[n], 1.0f));
        y2[t] = __floats2half2_rn(v.x * s, v.y * s);
    }
}

// Scatter: 32 lanes per edge, one packed-fp16 atomic per lane.
// 25.6M pk atomics (vs 51.2M scalar fp32 in the R1 baseline).
__global__ void scatter_kernel(const __half2* __restrict__ y2,
                               const int* __restrict__ src,
                               const int* __restrict__ dst,
                               __half2* __restrict__ agg2) {
    int t = blockIdx.x * blockDim.x + threadIdx.x;
    int e = t >> 5;          // edge index
    int c = t & 31;          // half2 column
    if (e < N_EDGES) {
        int s = src[e];      // broadcast within half-wave
        int d = dst[e];
        __half2 v = y2[(size_t)s * 32 + c];
        unsigned int vbits = *(unsigned int*)&v;
        __half2* addr = agg2 + (size_t)d * 32 + c;
        asm volatile("global_atomic_pk_add_f16 %0, %1, off"
                     :: "v"(addr), "v"(vbits) : "memory");
    }
}

// out[n][j] = rsqrt(max(in_deg[n],1)) * (agg[n][:] @ W)[j] + b[j]
// Block 256 = 32 nodes; thread: 2 nodes x 4 cols; W in LDS (float4 reads).
#define TN 32
__global__ void epilogue_kernel(const __half2* __restrict__ agg2,
                                const int* __restrict__ in_deg,
                                const float* __restrict__ W,
                                const float* __restrict__ b,
                                float* __restrict__ out) {
    __shared__ float Ws[D * D];
    {
        const float4* W4 = (const float4*)W;
        float4* Ws4 = (float4*)Ws;
        for (int i = threadIdx.x; i < D * D / 4; i += 256) Ws4[i] = W4[i];
    }
    __syncthreads();

    int jg = threadIdx.x & 15;        // cols [4*jg, 4*jg+4)
    int pr = threadIdx.x >> 4;        // node pair 0..15
    int n0 = blockIdx.x * TN + pr * 2;
    int n1 = n0 + 1;
    bool v0 = n0 < N_NODES, v1 = n1 < N_NODES;
    const __half2* a0h = agg2 + (size_t)(v0 ? n0 : 0) * 32;
    const __half2* a1h = agg2 + (size_t)(v1 ? n1 : 0) * 32;

    float a00 = 0.f, a01 = 0.f, a02 = 0.f, a03 = 0.f;
    float a10 = 0.f, a11 = 0.f, a12 = 0.f, a13 = 0.f;

#pragma unroll
    for (int k = 0; k < D; k += 4) {
        __half2 ha0 = a0h[k >> 1], ha1 = a0h[(k >> 1) + 1];
        __half2 hb0 = a1h[k >> 1], hb1 = a1h[(k >> 1) + 1];
        float4 xa = make_float4(__low2float(ha0), __high2float(ha0),
                                __low2float(ha1), __high2float(ha1));
        float4 xb = make_float4(__low2float(hb0), __high2float(hb0),
                                __low2float(hb1), __high2float(hb1));
        const float* wr = &Ws[k * D + 4 * jg];
        float4 w0 = *(const float4*)(wr);
        float4 w1 = *(const float4*)(wr + D);
        float4 w2 = *(const float4*)(wr + 2 * D);
        float4 w3 = *(const float4*)(wr + 3 * D);

        a00 = fmaf(xa.x, w0.x, a00); a01 = fmaf(xa.x, w0.y, a01);
        a02 = fmaf(xa.x, w0.z, a02); a03 = fmaf(xa.x, w0.w, a03);
        a00 = fmaf(xa.y, w1.x, a00); a01 = fmaf(xa.y, w1.y, a01);
        a02 = fmaf(xa.y, w1.z, a02); a03 = fmaf(xa.y, w1.w, a03);
        a00 = fmaf(xa.z, w2.x, a00); a01 = fmaf(xa.z, w2.y, a01);
        a02 = fmaf(xa.z, w2.z, a02); a03 = fmaf(xa.z, w2.w, a03);
        a00 = fmaf(xa.w, w3.x, a00); a01 = fmaf(xa.w, w3.y, a01);
        a02 = fmaf(xa.w, w3.z, a02); a03 = fmaf(xa.w, w3.w, a03);

        a10 = fmaf(xb.x, w0.x, a10); a11 = fmaf(xb.x, w0.y, a11);
        a12 = fmaf(xb.x, w0.z, a12); a13 = fmaf(xb.x, w0.w, a13);
        a10 = fmaf(xb.y, w1.x, a10); a11 = fmaf(xb.y, w1.y, a11);
        a12 = fmaf(xb.y, w1.z, a12); a13 = fmaf(xb.y, w1.w, a13);
        a10 = fmaf(xb.z, w2.x, a10); a11 = fmaf(xb.z, w2.y, a11);
        a12 = fmaf(xb.z, w2.z, a12); a13 = fmaf(xb.z, w2.w, a13);
        a10 = fmaf(xb.w, w3.x, a10); a11 = fmaf(xb.w, w3.y, a11);
        a12 = fmaf(xb.w, w3.z, a12); a13 = fmaf(xb.w, w3.w, a13);
    }

    float4 bb = *(const float4*)(b + 4 * jg);
    if (v0) {
        float s = rsqrtf(fmaxf((float)in_deg[n0], 1.0f));
        *(float4*)&out[(size_t)n0 * D + 4 * jg] =
            make_float4(fmaf(a00, s, bb.x), fmaf(a01, s, bb.y),
                        fmaf(a02, s, bb.z), fmaf(a03, s, bb.w));
    }
    if (v1) {
        float s = rsqrtf(fmaxf((float)in_deg[n1], 1.0f));
        *(float4*)&out[(size_t)n1 * D + 4 * jg] =
            make_float4(fmaf(a10, s, bb.x), fmaf(a11, s, bb.y),
                        fmaf(a12, s, bb.z), fmaf(a13, s, bb.w));
    }
}

extern "C" void kernel_launch(void* const* d_in, const int* in_sizes, int n_in,
                              void* d_out, int out_size, void* d_ws, size_t ws_size,
                              hipStream_t stream) {
    const float* x   = (const float*)d_in[0];
    const int*   src = (const int*)d_in[1];
    const int*   dst = (const int*)d_in[2];
    const float* W   = (const float*)d_in[3];
    const float* b   = (const float*)d_in[4];
    float* out = (float*)d_out;

    char* ws = (char*)d_ws;
    __half2* agg2  = (__half2*)(ws + AGG_OFF);
    int*     outdeg = (int*)(ws + OUTDEG_OFF);
    int*     indeg  = (int*)(ws + INDEG_OFF);
    __half2* y2    = (__half2*)(ws + Y_OFF);

    (void)hipMemsetAsync(d_ws, 0, ZERO_BYTES, stream);

    {
        int blocks = (N_EDGES / 4 + 255) / 256;
        degree_kernel<<<blocks, 256, 0, stream>>>(src, dst, outdeg, indeg);
    }
    {
        int total = N_NODES * (D / 2);
        int blocks = (total + 255) / 256;
        yscale_kernel<<<blocks, 256, 0, stream>>>(x, outdeg, y2);
    }
    {
        long long total = (long long)N_EDGES * 32;
        int blocks = (int)((total + 255) / 256);
        scatter_kernel<<<blocks, 256, 0, stream>>>(y2, src, dst, agg2);
    }
    {
        int blocks = (N_NODES + TN - 1) / TN;
        epilogue_kernel<<<blocks, 256, 0, stream>>>(agg2, indeg, W, b, out);
    }
}